// Round 10
// baseline (219.522 us; speedup 1.0000x reference)
//
#include <hip/hip_runtime.h>

// Fused chunked causal attention + RoPE for MI355X (gfx950).
// B=4, SLEN=4096, H=8, ZD=128, VD=256, CHUNK=1024 -> 16 chunks x 8 heads.
// fp32 in/out; fp16 MFMA 32x32x16, fp32 accum.
// Round 10: break the 256-reg/wave wall. Wave = 32q x 128v (acc 64 regs),
// block = 4 waves (2 q-groups x 2 v-halves), QTILE=64, launch_bounds(256,3)
// -> 3 blocks/CU = 12 waves/CU. QK^T duplicated across v-half waves (cheap).
// Grid 2048 non-uniform blocks, heavy-qt-first per XCD (LPT balance).
// LDS layouts/swizzles and all fragment math carried from r9.

#define NHEAD 8
#define ZDIM  128
#define VDIM  256
#define CHUNK 1024
#define QTILE 64    // q rows per block (2 groups x 32)
#define KT    32    // k rows per tile
#define NW    4

typedef _Float16 f16x8 __attribute__((ext_vector_type(8)));
typedef _Float16 f16x4 __attribute__((ext_vector_type(4)));
typedef __fp16   h16x2 __attribute__((ext_vector_type(2)));   // cvt_pkrtz return type
typedef float    f32x4  __attribute__((ext_vector_type(4)));
typedef float    f32x16 __attribute__((ext_vector_type(16)));
typedef unsigned int u32;

#define KSTRIDE 128   // halfs per K-lds row (256B rows; chunk^(row&7) XOR swizzle)
#define VSTRIDE 36    // halfs per V^T-lds row (32 + 4 pad)
#define LOG2E   1.44269504088896f
#define RTHR    11.5415603f   /* 8 nats in log2 domain: defer-max threshold */

__global__ __launch_bounds__(256, 3)
void attn_fused(const float* __restrict__ xq, const float* __restrict__ xk,
                const float* __restrict__ xv, const float* __restrict__ cosT,
                const float* __restrict__ sinT, float* __restrict__ out)
{
  __shared__ _Float16 Klds[2][KT * KSTRIDE];     // 16.0 KB
  __shared__ _Float16 Vlds[2][VDIM * VSTRIDE];   // 36.9 KB (transposed, swizzled)
  // total 52.9 KB -> 3 blocks/CU (158.7 KB of 160)

  // Swizzle: XCD = b&7 gets 16 ch x 16 qt; within an XCD, qt descends with
  // dispatch order (heavy-first -> LPT balance) and ch stays grouped for L2.
  const int b   = (int)blockIdx.x;
  const int idx = b >> 3;                        // 0..255 per XCD
  const int qt  = 15 - (idx >> 4);               // 15..0, heavy first
  const int ch  = (b & 7) * 16 + (idx & 15);     // 0..127
  const int h   = ch & 7;
  const int cb  = ch >> 3;

  const int tid  = threadIdx.x;
  const int w    = tid >> 6;                     // wave 0..3
  const int qg   = w >> 1;                       // q-group 0/1 (32 rows each)
  const int vh   = w & 1;                        // v-half 0/1 (128 cols each)
  const int lane = tid & 63;
  const int l31  = lane & 31;
  const int hi   = lane >> 5;                    // 0/1
  const int vswz = (l31 >> 3) & 3;               // V read kblk XOR
  const int kswz = l31 & 7;                      // K read chunk XOR (row&7)

  const size_t row0 = (size_t)cb * CHUNK;

  // staging thread mapping (256 threads cover 32x128 K and 32x256 V)
  const int kr    = tid >> 3;             // K row 0..31
  const int kt8   = tid & 7;              // K chunk pair {kt8, kt8+8}
  const int vg    = tid >> 5;             // 0..7 -> V rows vg*4..+3
  const int vc0   = (tid & 31) * 8;       // V col group
  const int vsw   = tid & 3;              // V write kblk XOR
  const int vflip = ((tid >> 2) & 1) * 4; // V write sub-slot XOR ((vcol>>5)&1)*4
  const int kblk  = vg >> 1;
  const int inb   = (vg & 1) * 4;

  const int wq0 = qt * QTILE + qg * 32;          // wave's lowest q-row
  const int qgr = wq0 + l31;                     // this lane's q-row

  // ---- Q -> registers as 32x32x16 B-frags (RoPE'd, pre-scaled by log2e) ----
  f16x8 qfrag[8];
  {
    const float* qp = xq + (row0 + qgr) * (size_t)(NHEAD * ZDIM) + h * ZDIM;
    const float* cq = cosT + qgr * (ZDIM / 2);
    const float* sq = sinT + qgr * (ZDIM / 2);
#pragma unroll
    for (int dblk = 0; dblk < 8; ++dblk) {
      const int d0 = dblk * 16 + hi * 8;
      f32x4 a  = *(const f32x4*)(qp + d0);
      f32x4 b2 = *(const f32x4*)(qp + d0 + 4);
      f32x4 cv = *(const f32x4*)(cq + (d0 >> 1));
      f32x4 sv = *(const f32x4*)(sq + (d0 >> 1));
      union { h16x2 h2[4]; f16x8 v; } fr;
#pragma unroll
      for (int p = 0; p < 4; ++p) {
        const float xr = (p < 2 ? a[2 * p] : b2[2 * p - 4]);
        const float xi = (p < 2 ? a[2 * p + 1] : b2[2 * p - 3]);
        fr.h2[p] = __builtin_amdgcn_cvt_pkrtz((xr * cv[p] - xi * sv[p]) * LOG2E,
                                              (xr * sv[p] + xi * cv[p]) * LOG2E);
      }
      qfrag[dblk] = fr.v;
    }
  }

  const f32x16 zf = {};
  f32x16 acc[4];                                  // O^T: 128 vcols (this half) x 32 q
#pragma unroll
  for (int g = 0; g < 4; ++g) acc[g] = zf;
  float mrun = -1e30f;                            // per-lane (its q), log2 domain
  float lrun = 0.f;                               // per-lane partial denominator

  const int nkt = 2 * qt + 2;
  int buf = 0;

  for (int kt = 0; kt < nkt; ++kt) {
    const int ktb = kt * KT;
    // ---- stage K tile with RoPE -> Klds[buf]; chunks {kt8, kt8+8}, slot = c^(kr&7) ----
    {
      const int krow = ktb + kr;
      const float* kpb = xk + (row0 + krow) * (size_t)(NHEAD * ZDIM) + h * ZDIM;
      const float* ckb = cosT + krow * (ZDIM / 2);
      const float* skb = sinT + krow * (ZDIM / 2);
      f32x4 a0 = *(const f32x4*)(kpb + 8 * kt8);
      f32x4 a1 = *(const f32x4*)(kpb + 8 * kt8 + 4);
      f32x4 ca = *(const f32x4*)(ckb + 4 * kt8);
      f32x4 sa = *(const f32x4*)(skb + 4 * kt8);
      f32x4 b0 = *(const f32x4*)(kpb + 8 * kt8 + 64);
      f32x4 b1 = *(const f32x4*)(kpb + 8 * kt8 + 68);
      f32x4 cbv = *(const f32x4*)(ckb + 4 * kt8 + 32);
      f32x4 sbv = *(const f32x4*)(skb + 4 * kt8 + 32);
      union { h16x2 h2[4]; f16x8 v; } koA, koB;
#pragma unroll
      for (int p = 0; p < 4; ++p) {
        const float xrA = (p < 2 ? a0[2 * p] : a1[2 * p - 4]);
        const float xiA = (p < 2 ? a0[2 * p + 1] : a1[2 * p - 3]);
        koA.h2[p] = __builtin_amdgcn_cvt_pkrtz(xrA * ca[p] - xiA * sa[p],
                                               xrA * sa[p] + xiA * ca[p]);
        const float xrB = (p < 2 ? b0[2 * p] : b1[2 * p - 4]);
        const float xiB = (p < 2 ? b0[2 * p + 1] : b1[2 * p - 3]);
        koB.h2[p] = __builtin_amdgcn_cvt_pkrtz(xrB * cbv[p] - xiB * sbv[p],
                                               xrB * sbv[p] + xiB * cbv[p]);
      }
      const int sw = kr & 7;
      *(f16x8*)&Klds[buf][kr * KSTRIDE + ((kt8 ^ sw) * 8)]       = koA.v;
      *(f16x8*)&Klds[buf][kr * KSTRIDE + (((kt8 + 8) ^ sw) * 8)] = koB.v;
    }
    // ---- stage V tile transposed -> Vlds[buf] (kblk^vsw, inb^vflip) ----
    {
      const int vrow = ktb + vg * 4;
      const float* vp = xv + (row0 + vrow) * (size_t)(NHEAD * VDIM) + h * VDIM + vc0;
      f32x4 v0 = *(const f32x4*)(vp);         f32x4 v1 = *(const f32x4*)(vp + 4);
      f32x4 v2 = *(const f32x4*)(vp + 2048);  f32x4 v3 = *(const f32x4*)(vp + 2052);
      f32x4 v4 = *(const f32x4*)(vp + 4096);  f32x4 v5 = *(const f32x4*)(vp + 4100);
      f32x4 v6 = *(const f32x4*)(vp + 6144);  f32x4 v7 = *(const f32x4*)(vp + 6148);
#pragma unroll
      for (int ci = 0; ci < 8; ++ci) {
        const float e0 = (ci < 4 ? v0[ci] : v1[ci - 4]);
        const float e1 = (ci < 4 ? v2[ci] : v3[ci - 4]);
        const float e2 = (ci < 4 ? v4[ci] : v5[ci - 4]);
        const float e3 = (ci < 4 ? v6[ci] : v7[ci - 4]);
        union { h16x2 a2[2]; f16x4 v; } t;
        t.a2[0] = __builtin_amdgcn_cvt_pkrtz(e0, e1);
        t.a2[1] = __builtin_amdgcn_cvt_pkrtz(e2, e3);
        *(f16x4*)&Vlds[buf][(vc0 + ci) * VSTRIDE + ((kblk ^ vsw) * 8) + (inb ^ vflip)] = t.v;
      }
    }
    __syncthreads();   // staging visible; dbuf keeps one barrier/tile safe

    // ---- per-wave skip of fully-masked tiles ----
    if (ktb <= wq0 + 31) {
      // ---- S^T = K Q : col=l31=q, row=k-local (duplicated across v-halves) ----
      f32x16 s = {};
      __builtin_amdgcn_s_setprio(1);
#pragma unroll
      for (int dblk = 0; dblk < 8; ++dblk) {
        f16x8 kf = *(const f16x8*)&Klds[buf][l31 * KSTRIDE + (((dblk * 2 + hi) ^ kswz) * 8)];
        s = __builtin_amdgcn_mfma_f32_32x32x16_f16(kf, qfrag[dblk], s, 0, 0, 0);
      }
      __builtin_amdgcn_s_setprio(0);

      // ---- causal mask (partial tiles only); k_local = (r&3)+8*(r>>2)+4*hi ----
      if (ktb + 31 > wq0) {
#pragma unroll
        for (int r = 0; r < 16; ++r) {
          const int kg = ktb + ((r & 3) + 8 * (r >> 2) + 4 * hi);
          if (kg > qgr) s[r] = -1.0e9f;
        }
      }

      // ---- softmax: lane-local max + one cross-half shuffle ----
      float m = s[0];
#pragma unroll
      for (int r = 1; r < 16; ++r) m = fmaxf(m, s[r]);
      m = fmaxf(m, __shfl_xor(m, 32));
      const bool need = (m > mrun + RTHR);
      if (__any(need)) {
        const float Mn = fmaxf(mrun, m);
        const float al = exp2f(mrun - Mn);
        mrun = Mn;
        lrun *= al;
#pragma unroll
        for (int r = 0; r < 16; ++r) {
          const float alr = __shfl(al, (r & 3) + 8 * (r >> 2) + 4 * hi);
#pragma unroll
          for (int g = 0; g < 4; ++g) acc[g][r] *= alr;
        }
      }
      float lsum = 0.f;
#pragma unroll
      for (int r = 0; r < 16; ++r) {
        s[r] = exp2f(s[r] - mrun);   // P in place of S
        lsum += s[r];
      }
      lrun += lsum;

      // ---- P -> fp16 A-frags in registers, then PV (this wave's 128 vcols) ----
#pragma unroll
      for (int kb = 0; kb < 2; ++kb) {
        union { h16x2 h; u32 u; } A_, B_, C_, D_;
        A_.h = __builtin_amdgcn_cvt_pkrtz(s[8 * kb + 0], s[8 * kb + 1]);
        B_.h = __builtin_amdgcn_cvt_pkrtz(s[8 * kb + 2], s[8 * kb + 3]);
        C_.h = __builtin_amdgcn_cvt_pkrtz(s[8 * kb + 4], s[8 * kb + 5]);
        D_.h = __builtin_amdgcn_cvt_pkrtz(s[8 * kb + 6], s[8 * kb + 7]);
        const u32 G1 = hi ? A_.u : C_.u;
        const u32 G2 = hi ? B_.u : D_.u;
        const u32 G1s = (u32)__shfl_xor((int)G1, 32);
        const u32 G2s = (u32)__shfl_xor((int)G2, 32);
        union { u32 u[4]; f16x8 v; } af;
        af.u[0] = hi ? G1s : A_.u;
        af.u[1] = hi ? G2s : B_.u;
        af.u[2] = hi ? C_.u : G1s;
        af.u[3] = hi ? D_.u : G2s;
        __builtin_amdgcn_s_setprio(1);
#pragma unroll
        for (int g = 0; g < 4; ++g) {
          const int vcol = vh * 128 + g * 32 + l31;
          const int ck = (((kb * 2 + hi) ^ vswz) * 8);
          const int fl = (g & 1) * 4;   // (vcol>>5)&1 with vh*128 even in bit5-parity
          union { f16x4 h4[2]; f16x8 v; } bf;
          bf.h4[0] = *(const f16x4*)&Vlds[buf][vcol * VSTRIDE + ck + fl];
          bf.h4[1] = *(const f16x4*)&Vlds[buf][vcol * VSTRIDE + ck + (fl ^ 4)];
          acc[g] = __builtin_amdgcn_mfma_f32_32x32x16_f16(af.v, bf.v, acc[g], 0, 0, 0);
        }
        __builtin_amdgcn_s_setprio(0);
      }
    }
    buf ^= 1;
  }

  // ---- epilogue: denom reduce (1 shuffle), per-row linv broadcast, store ----
  const float ls = lrun + __shfl_xor(lrun, 32);
  const float linv = 1.0f / ls;
#pragma unroll
  for (int r = 0; r < 16; ++r) {
    const int qloc = (r & 3) + 8 * (r >> 2) + 4 * hi;
    const float lr = __shfl(linv, qloc);
    const size_t ob = (row0 + wq0 + qloc) * (size_t)(NHEAD * VDIM) + h * VDIM + vh * 128 + l31;
#pragma unroll
    for (int g = 0; g < 4; ++g)
      out[ob + g * 32] = acc[g][r] * lr;
  }
}

extern "C" void kernel_launch(void* const* d_in, const int* in_sizes, int n_in,
                              void* d_out, int out_size, void* d_ws, size_t ws_size,
                              hipStream_t stream) {
  const float* xq   = (const float*)d_in[0];
  const float* xk   = (const float*)d_in[1];
  const float* xv   = (const float*)d_in[2];
  // d_in[3] = mask (unused: causal mask computed analytically)
  const float* cosT = (const float*)d_in[4];
  const float* sinT = (const float*)d_in[5];
  float* out = (float*)d_out;

  dim3 grid(2048);   // 16 qt x 128 ch, heavy-first per XCD, 3 blocks/CU
  dim3 block(256);   // 4 waves: 2 q-groups x 2 v-halves
  attn_fused<<<grid, block, 0, stream>>>(xq, xk, xv, cosT, sinT, out);
}